// Round 3
// baseline (196.454 us; speedup 1.0000x reference)
//
#include <hip/hip_runtime.h>
#include <math.h>

namespace {

constexpr int D   = 32;
constexpr int H   = 128;
constexpr int WS  = 36;    // padded row stride: 8 lane-quads hit banks 4*kq -> all 32 banks once
constexpr int L   = 8;     // lanes per batch element
constexpr int THREADS = 256;      // 4 waves
constexpr int EPB = THREADS / L;  // 32 elements per block
constexpr int KPL = H / L;        // 16 hidden units per lane

__device__ __forceinline__ float fast_tanh(float z) {
  float e = __expf(2.0f * z);
  return 1.0f - 2.0f * __builtin_amdgcn_rcpf(e + 1.0f);
}

__global__ __launch_bounds__(THREADS, 2) void fpe_kernel(
    const float* __restrict__ xg, const float* __restrict__ tg,
    const float* __restrict__ betag, const float* __restrict__ W1g,
    const float* __restrict__ b1g, const float* __restrict__ W2g,
    const float* __restrict__ b2g, float* __restrict__ out, int Btot)
{
  __shared__ float W1T[H * WS];  // W1T[k][i], i<33; [33]=b1_k, [34]=c_k
  __shared__ float W2r[H * WS];  // W2r[k][j], j<32
  __shared__ float b2s[D];

  const int tid = threadIdx.x;
  const int e   = tid >> 3;      // element within block
  const int kq  = tid & 7;       // k-eighth
  const int b   = blockIdx.x * EPB + e;
  const bool valid = (b < Btot);
  const int bc = valid ? b : 0;

  // ---- per-element global loads issued first (latency hides under staging)
  float4 xr[8];
  const float4* xv = reinterpret_cast<const float4*>(xg + (size_t)bc * D);
  #pragma unroll
  for (int q = 0; q < 8; ++q) xr[q] = xv[q];
  const float tval = tg[bc];
  const float hb   = 0.5f * betag[bc];

  // ---- stage weights (W1 transposed), biases
  for (int n = tid; n < 33 * H; n += THREADS) {
    int i = n >> 7, k = n & (H - 1);
    W1T[k * WS + i] = W1g[n];
  }
  for (int n = tid; n < H * D; n += THREADS) {
    int k = n >> 5, j = n & (D - 1);
    W2r[k * WS + j] = W2g[n];
  }
  if (tid < H) W1T[tid * WS + 33] = b1g[tid];
  if (tid < D) b2s[tid] = b2g[tid];
  __syncthreads();

  // c_k = sum_j W1[j,k]*W2[k,j] (batch-independent)
  if (tid < H) {
    const float* wa = W1T + tid * WS;
    const float* wb = W2r + tid * WS;
    float c0 = 0, c1 = 0, c2 = 0, c3 = 0;
    #pragma unroll
    for (int j = 0; j < D; j += 4) {
      c0 = fmaf(wa[j + 0], wb[j + 0], c0);
      c1 = fmaf(wa[j + 1], wb[j + 1], c1);
      c2 = fmaf(wa[j + 2], wb[j + 2], c2);
      c3 = fmaf(wa[j + 3], wb[j + 3], c3);
    }
    W1T[tid * WS + 34] = (c0 + c1) + (c2 + c3);
  }
  __syncthreads();

  // ---- unpack x
  float x[D];
  #pragma unroll
  for (int q = 0; q < 8; ++q) {
    x[4*q+0] = xr[q].x; x[4*q+1] = xr[q].y; x[4*q+2] = xr[q].z; x[4*q+3] = xr[q].w;
  }

  float ps[D], pd[D], hreg[KPL];
  #pragma unroll
  for (int j = 0; j < D; ++j) { ps[j] = 0.0f; pd[j] = 0.0f; }

  // ================= Pass A: z, h (regs), partial s & ds/dt over this lane's k's
  #pragma unroll
  for (int n = 0; n < KPL; ++n) {
    const int k = L * n + kq;
    const float4* wa = reinterpret_cast<const float4*>(W1T + k * WS);
    const float4* wb = reinterpret_cast<const float4*>(W2r + k * WS);
    const float4 a8 = wa[8];                 // {W1[32,k], b1_k, c_k, pad}
    float z0 = a8.y, z1 = 0.0f, z2 = 0.0f, z3 = 0.0f;
    #pragma unroll
    for (int q = 0; q < 8; ++q) {
      float4 a = wa[q];
      z0 = fmaf(a.x, x[4*q+0], z0);
      z1 = fmaf(a.y, x[4*q+1], z1);
      z2 = fmaf(a.z, x[4*q+2], z2);
      z3 = fmaf(a.w, x[4*q+3], z3);
    }
    float z  = ((z0 + z1) + (z2 + z3)) + a8.x * tval;
    float hh = fast_tanh(z);
    hreg[n] = hh;
    float g = 1.0f - hh * hh;
    float r = g * a8.x;
    #pragma unroll
    for (int q = 0; q < 8; ++q) {
      float4 w2 = wb[q];
      ps[4*q+0] = fmaf(w2.x, hh, ps[4*q+0]);
      ps[4*q+1] = fmaf(w2.y, hh, ps[4*q+1]);
      ps[4*q+2] = fmaf(w2.z, hh, ps[4*q+2]);
      ps[4*q+3] = fmaf(w2.w, hh, ps[4*q+3]);
      pd[4*q+0] = fmaf(w2.x, r,  pd[4*q+0]);
      pd[4*q+1] = fmaf(w2.y, r,  pd[4*q+1]);
      pd[4*q+2] = fmaf(w2.z, r,  pd[4*q+2]);
      pd[4*q+3] = fmaf(w2.w, r,  pd[4*q+3]);
    }
  }

  // ---- allreduce s, dsdt across the 8 lanes of this element
  #pragma unroll
  for (int j = 0; j < D; ++j) {
    ps[j] += __shfl_xor(ps[j], 1);
    ps[j] += __shfl_xor(ps[j], 2);
    ps[j] += __shfl_xor(ps[j], 4);
    pd[j] += __shfl_xor(pd[j], 1);
    pd[j] += __shfl_xor(pd[j], 2);
    pd[j] += __shfl_xor(pd[j], 4);
  }

  // v = 2s + x ; A = dsdt - hb*s
  float v[D], A[D];
  #pragma unroll
  for (int q = 0; q < 8; ++q) {
    float4 bq = reinterpret_cast<const float4*>(b2s)[q];
    float s0 = ps[4*q+0] + bq.x, s1 = ps[4*q+1] + bq.y;
    float s2 = ps[4*q+2] + bq.z, s3 = ps[4*q+3] + bq.w;
    v[4*q+0] = fmaf(2.0f, s0, x[4*q+0]);
    v[4*q+1] = fmaf(2.0f, s1, x[4*q+1]);
    v[4*q+2] = fmaf(2.0f, s2, x[4*q+2]);
    v[4*q+3] = fmaf(2.0f, s3, x[4*q+3]);
    A[4*q+0] = fmaf(-hb, s0, pd[4*q+0]);
    A[4*q+1] = fmaf(-hb, s1, pd[4*q+1]);
    A[4*q+2] = fmaf(-hb, s2, pd[4*q+2]);
    A[4*q+3] = fmaf(-hb, s3, pd[4*q+3]);
  }

  // ================= Pass B: q_k and partial grad
  float pg[D];
  #pragma unroll
  for (int j = 0; j < D; ++j) pg[j] = 0.0f;

  #pragma unroll
  for (int n = 0; n < KPL; ++n) {
    const int k = L * n + kq;
    const float4* wa = reinterpret_cast<const float4*>(W1T + k * WS);
    const float4* wb = reinterpret_cast<const float4*>(W2r + k * WS);

    float m0 = 0, m1 = 0, m2 = 0, m3 = 0;
    #pragma unroll
    for (int q = 0; q < 8; ++q) {
      float4 w2 = wb[q];
      m0 = fmaf(w2.x, v[4*q+0], m0);
      m1 = fmaf(w2.y, v[4*q+1], m1);
      m2 = fmaf(w2.z, v[4*q+2], m2);
      m3 = fmaf(w2.w, v[4*q+3], m3);
    }
    float m  = (m0 + m1) + (m2 + m3);
    float hh = hreg[n];
    float g  = 1.0f - hh * hh;
    float c  = wa[8].z;
    float qk = g * fmaf(-2.0f * c, hh, m);

    #pragma unroll
    for (int q = 0; q < 8; ++q) {
      float4 a = wa[q];
      pg[4*q+0] = fmaf(a.x, qk, pg[4*q+0]);
      pg[4*q+1] = fmaf(a.y, qk, pg[4*q+1]);
      pg[4*q+2] = fmaf(a.z, qk, pg[4*q+2]);
      pg[4*q+3] = fmaf(a.w, qk, pg[4*q+3]);
    }
  }

  // ---- allreduce grad partials
  #pragma unroll
  for (int j = 0; j < D; ++j) {
    pg[j] += __shfl_xor(pg[j], 1);
    pg[j] += __shfl_xor(pg[j], 2);
    pg[j] += __shfl_xor(pg[j], 4);
  }

  // ---- distributed L1: lane kq handles j = 4*kq .. 4*kq+3
  const int j0 = 4 * kq;
  float acc = fabsf(fmaf(-hb, pg[j0+0], A[j0+0]))
            + fabsf(fmaf(-hb, pg[j0+1], A[j0+1]))
            + fabsf(fmaf(-hb, pg[j0+2], A[j0+2]))
            + fabsf(fmaf(-hb, pg[j0+3], A[j0+3]));
  acc += __shfl_xor(acc, 1);
  acc += __shfl_xor(acc, 2);
  acc += __shfl_xor(acc, 4);

  if (valid && kq == 0) out[b] = acc * (1.0f / 32.0f);
}

} // namespace

extern "C" void kernel_launch(void* const* d_in, const int* in_sizes, int n_in,
                              void* d_out, int out_size, void* d_ws, size_t ws_size,
                              hipStream_t stream) {
  const float* x    = (const float*)d_in[0];
  const float* t    = (const float*)d_in[1];
  const float* beta = (const float*)d_in[2];
  const float* W1   = (const float*)d_in[3];
  const float* b1   = (const float*)d_in[4];
  const float* W2   = (const float*)d_in[5];
  const float* b2   = (const float*)d_in[6];
  float* out = (float*)d_out;

  const int Btot = in_sizes[1];  // t is [B,1]
  const int grid = (Btot + EPB - 1) / EPB;
  hipLaunchKernelGGL(fpe_kernel, dim3(grid), dim3(THREADS), 0, stream,
                     x, t, beta, W1, b1, W2, b2, out, Btot);
}

// Round 4
// 134.770 us; speedup vs baseline: 1.4577x; 1.4577x over previous
//
#include <hip/hip_runtime.h>
#include <math.h>

namespace {

constexpr int D   = 32;
constexpr int H   = 128;
constexpr int WS  = 36;    // padded row stride: 8 lane-groups hit banks 4*kq -> all 32 banks once
constexpr int L   = 8;     // lanes per batch element
constexpr int THREADS = 256;      // 4 waves
constexpr int EPB = THREADS / L;  // 32 elements per block
constexpr int KPL = H / L;        // 16 hidden units per lane

__device__ __forceinline__ float fast_tanh(float z) {
  float e = __expf(2.0f * z);
  return 1.0f - 2.0f * __builtin_amdgcn_rcpf(e + 1.0f);
}

// NOTE: min-waves/EU deliberately 1 — capping VGPRs at 128 (R3, launch_bounds(256,2))
// spilled ~150 live floats to scratch: WRITE_SIZE 64KB -> 366MB, 5x slowdown.
__global__ __launch_bounds__(THREADS, 1) void fpe_kernel(
    const float* __restrict__ xg, const float* __restrict__ tg,
    const float* __restrict__ betag, const float* __restrict__ W1g,
    const float* __restrict__ b1g, const float* __restrict__ W2g,
    const float* __restrict__ b2g, float* __restrict__ out, int Btot)
{
  __shared__ float W1T[H * WS];  // W1T[k][i], i<33; [33]=b1_k, [34]=c_k
  __shared__ float W2r[H * WS];  // W2r[k][j], j<32
  __shared__ float b2s[D];

  const int tid = threadIdx.x;
  const int e   = tid >> 3;      // element within block
  const int kq  = tid & 7;       // k-eighth
  const int b   = blockIdx.x * EPB + e;
  const bool valid = (b < Btot);
  const int bc = valid ? b : 0;

  // ---- per-element global loads issued first (latency hides under staging)
  float4 xr[8];
  const float4* xv = reinterpret_cast<const float4*>(xg + (size_t)bc * D);
  #pragma unroll
  for (int q = 0; q < 8; ++q) xr[q] = xv[q];
  const float tval = tg[bc];
  const float hb   = 0.5f * betag[bc];

  // ---- stage weights (W1 transposed), biases
  for (int n = tid; n < 33 * H; n += THREADS) {
    int i = n >> 7, k = n & (H - 1);
    W1T[k * WS + i] = W1g[n];
  }
  for (int n = tid; n < H * D; n += THREADS) {
    int k = n >> 5, j = n & (D - 1);
    W2r[k * WS + j] = W2g[n];
  }
  if (tid < H) W1T[tid * WS + 33] = b1g[tid];
  if (tid < D) b2s[tid] = b2g[tid];
  __syncthreads();

  // c_k = sum_j W1[j,k]*W2[k,j] (batch-independent)
  if (tid < H) {
    const float* wa = W1T + tid * WS;
    const float* wb = W2r + tid * WS;
    float c0 = 0, c1 = 0, c2 = 0, c3 = 0;
    #pragma unroll
    for (int j = 0; j < D; j += 4) {
      c0 = fmaf(wa[j + 0], wb[j + 0], c0);
      c1 = fmaf(wa[j + 1], wb[j + 1], c1);
      c2 = fmaf(wa[j + 2], wb[j + 2], c2);
      c3 = fmaf(wa[j + 3], wb[j + 3], c3);
    }
    W1T[tid * WS + 34] = (c0 + c1) + (c2 + c3);
  }
  __syncthreads();

  // ---- unpack x
  float x[D];
  #pragma unroll
  for (int q = 0; q < 8; ++q) {
    x[4*q+0] = xr[q].x; x[4*q+1] = xr[q].y; x[4*q+2] = xr[q].z; x[4*q+3] = xr[q].w;
  }

  float ps[D], pd[D], hreg[KPL];
  #pragma unroll
  for (int j = 0; j < D; ++j) { ps[j] = 0.0f; pd[j] = 0.0f; }

  // ================= Pass A: z, h (regs), partial s & ds/dt over this lane's k's
  #pragma unroll
  for (int n = 0; n < KPL; ++n) {
    const int k = L * n + kq;
    const float4* wa = reinterpret_cast<const float4*>(W1T + k * WS);
    const float4* wb = reinterpret_cast<const float4*>(W2r + k * WS);
    const float4 a8 = wa[8];                 // {W1[32,k], b1_k, c_k, pad}
    float z0 = a8.y, z1 = 0.0f, z2 = 0.0f, z3 = 0.0f;
    #pragma unroll
    for (int q = 0; q < 8; ++q) {
      float4 a = wa[q];
      z0 = fmaf(a.x, x[4*q+0], z0);
      z1 = fmaf(a.y, x[4*q+1], z1);
      z2 = fmaf(a.z, x[4*q+2], z2);
      z3 = fmaf(a.w, x[4*q+3], z3);
    }
    float z  = ((z0 + z1) + (z2 + z3)) + a8.x * tval;
    float hh = fast_tanh(z);
    hreg[n] = hh;
    float g = 1.0f - hh * hh;
    float r = g * a8.x;
    #pragma unroll
    for (int q = 0; q < 8; ++q) {
      float4 w2 = wb[q];
      ps[4*q+0] = fmaf(w2.x, hh, ps[4*q+0]);
      ps[4*q+1] = fmaf(w2.y, hh, ps[4*q+1]);
      ps[4*q+2] = fmaf(w2.z, hh, ps[4*q+2]);
      ps[4*q+3] = fmaf(w2.w, hh, ps[4*q+3]);
      pd[4*q+0] = fmaf(w2.x, r,  pd[4*q+0]);
      pd[4*q+1] = fmaf(w2.y, r,  pd[4*q+1]);
      pd[4*q+2] = fmaf(w2.z, r,  pd[4*q+2]);
      pd[4*q+3] = fmaf(w2.w, r,  pd[4*q+3]);
    }
  }

  // ---- allreduce s, dsdt across the 8 lanes of this element
  #pragma unroll
  for (int j = 0; j < D; ++j) {
    ps[j] += __shfl_xor(ps[j], 1);
    ps[j] += __shfl_xor(ps[j], 2);
    ps[j] += __shfl_xor(ps[j], 4);
    pd[j] += __shfl_xor(pd[j], 1);
    pd[j] += __shfl_xor(pd[j], 2);
    pd[j] += __shfl_xor(pd[j], 4);
  }

  // x <- v = 2s + x ; pd <- A = dsdt - hb*s   (ps dies here; shrinks live set)
  #pragma unroll
  for (int q = 0; q < 8; ++q) {
    float4 bq = reinterpret_cast<const float4*>(b2s)[q];
    float s0 = ps[4*q+0] + bq.x, s1 = ps[4*q+1] + bq.y;
    float s2 = ps[4*q+2] + bq.z, s3 = ps[4*q+3] + bq.w;
    x[4*q+0] = fmaf(2.0f, s0, x[4*q+0]);
    x[4*q+1] = fmaf(2.0f, s1, x[4*q+1]);
    x[4*q+2] = fmaf(2.0f, s2, x[4*q+2]);
    x[4*q+3] = fmaf(2.0f, s3, x[4*q+3]);
    pd[4*q+0] = fmaf(-hb, s0, pd[4*q+0]);
    pd[4*q+1] = fmaf(-hb, s1, pd[4*q+1]);
    pd[4*q+2] = fmaf(-hb, s2, pd[4*q+2]);
    pd[4*q+3] = fmaf(-hb, s3, pd[4*q+3]);
  }

  // ================= Pass B: q_k and partial grad
  float pg[D];
  #pragma unroll
  for (int j = 0; j < D; ++j) pg[j] = 0.0f;

  #pragma unroll
  for (int n = 0; n < KPL; ++n) {
    const int k = L * n + kq;
    const float4* wa = reinterpret_cast<const float4*>(W1T + k * WS);
    const float4* wb = reinterpret_cast<const float4*>(W2r + k * WS);

    float m0 = 0, m1 = 0, m2 = 0, m3 = 0;
    #pragma unroll
    for (int q = 0; q < 8; ++q) {
      float4 w2 = wb[q];
      m0 = fmaf(w2.x, x[4*q+0], m0);
      m1 = fmaf(w2.y, x[4*q+1], m1);
      m2 = fmaf(w2.z, x[4*q+2], m2);
      m3 = fmaf(w2.w, x[4*q+3], m3);
    }
    float m  = (m0 + m1) + (m2 + m3);
    float hh = hreg[n];
    float g  = 1.0f - hh * hh;
    float c  = wa[8].z;
    float qk = g * fmaf(-2.0f * c, hh, m);

    #pragma unroll
    for (int q = 0; q < 8; ++q) {
      float4 a = wa[q];
      pg[4*q+0] = fmaf(a.x, qk, pg[4*q+0]);
      pg[4*q+1] = fmaf(a.y, qk, pg[4*q+1]);
      pg[4*q+2] = fmaf(a.z, qk, pg[4*q+2]);
      pg[4*q+3] = fmaf(a.w, qk, pg[4*q+3]);
    }
  }

  // ---- allreduce grad partials
  #pragma unroll
  for (int j = 0; j < D; ++j) {
    pg[j] += __shfl_xor(pg[j], 1);
    pg[j] += __shfl_xor(pg[j], 2);
    pg[j] += __shfl_xor(pg[j], 4);
  }

  // ---- distributed L1: lane kq handles j = 4*kq .. 4*kq+3   (pd holds A)
  const int j0 = 4 * kq;
  float acc = fabsf(fmaf(-hb, pg[j0+0], pd[j0+0]))
            + fabsf(fmaf(-hb, pg[j0+1], pd[j0+1]))
            + fabsf(fmaf(-hb, pg[j0+2], pd[j0+2]))
            + fabsf(fmaf(-hb, pg[j0+3], pd[j0+3]));
  acc += __shfl_xor(acc, 1);
  acc += __shfl_xor(acc, 2);
  acc += __shfl_xor(acc, 4);

  if (valid && kq == 0) out[b] = acc * (1.0f / 32.0f);
}

} // namespace

extern "C" void kernel_launch(void* const* d_in, const int* in_sizes, int n_in,
                              void* d_out, int out_size, void* d_ws, size_t ws_size,
                              hipStream_t stream) {
  const float* x    = (const float*)d_in[0];
  const float* t    = (const float*)d_in[1];
  const float* beta = (const float*)d_in[2];
  const float* W1   = (const float*)d_in[3];
  const float* b1   = (const float*)d_in[4];
  const float* W2   = (const float*)d_in[5];
  const float* b2   = (const float*)d_in[6];
  float* out = (float*)d_out;

  const int Btot = in_sizes[1];  // t is [B,1]
  const int grid = (Btot + EPB - 1) / EPB;
  hipLaunchKernelGGL(fpe_kernel, dim3(grid), dim3(THREADS), 0, stream,
                     x, t, beta, W1, b1, W2, b2, out, Btot);
}

// Round 5
// 30.369 us; speedup vs baseline: 6.4690x; 4.4378x over previous
//
#include <hip/hip_runtime.h>
#include <math.h>

namespace {

constexpr int D   = 32;
constexpr int H   = 128;
constexpr int WS  = 36;    // padded row stride: 8 lane-groups hit banks 4*kq -> all 32 banks once
constexpr int L   = 8;     // lanes per batch element
constexpr int THREADS = 256;      // 4 waves
constexpr int EPB = THREADS / L;  // 32 elements per block
constexpr int KPL = H / L;        // 16 hidden units per lane

__device__ __forceinline__ float fast_tanh(float z) {
  float e = __expf(2.0f * z);
  return 1.0f - 2.0f * __builtin_amdgcn_rcpf(e + 1.0f);
}

// launch_bounds(256,1): R3's (256,2) capped VGPRs at 128 -> scratch spills.
// #pragma unroll 2 (NOT full): full unroll let the scheduler hoist ~1100 floats
// of LDS loads, exploding live ranges -> spills even at 256 VGPRs (R4).
__global__ __launch_bounds__(THREADS, 1) void fpe_kernel(
    const float* __restrict__ xg, const float* __restrict__ tg,
    const float* __restrict__ betag, const float* __restrict__ W1g,
    const float* __restrict__ b1g, const float* __restrict__ W2g,
    const float* __restrict__ b2g, float* __restrict__ out, int Btot)
{
  __shared__ float W1T[H * WS];  // W1T[k][i], i<33; [33]=b1_k, [34]=c_k
  __shared__ float W2r[H * WS];  // W2r[k][j], j<32
  __shared__ float b2s[D];

  const int tid = threadIdx.x;
  const int e   = tid >> 3;      // element within block
  const int kq  = tid & 7;       // k-eighth
  const int b   = blockIdx.x * EPB + e;
  const bool valid = (b < Btot);
  const int bc = valid ? b : 0;

  // ---- per-element global loads issued first (latency hides under staging)
  float4 xr[8];
  const float4* xv = reinterpret_cast<const float4*>(xg + (size_t)bc * D);
  #pragma unroll
  for (int q = 0; q < 8; ++q) xr[q] = xv[q];
  const float tval = tg[bc];
  const float hb   = 0.5f * betag[bc];

  // ---- stage weights (W1 transposed), biases
  for (int n = tid; n < 33 * H; n += THREADS) {
    int i = n >> 7, k = n & (H - 1);
    W1T[k * WS + i] = W1g[n];
  }
  for (int n = tid; n < H * D; n += THREADS) {
    int k = n >> 5, j = n & (D - 1);
    W2r[k * WS + j] = W2g[n];
  }
  if (tid < H) W1T[tid * WS + 33] = b1g[tid];
  if (tid < D) b2s[tid] = b2g[tid];
  __syncthreads();

  // c_k = sum_j W1[j,k]*W2[k,j] (batch-independent)
  if (tid < H) {
    const float* wa = W1T + tid * WS;
    const float* wb = W2r + tid * WS;
    float c0 = 0, c1 = 0, c2 = 0, c3 = 0;
    #pragma unroll
    for (int j = 0; j < D; j += 4) {
      c0 = fmaf(wa[j + 0], wb[j + 0], c0);
      c1 = fmaf(wa[j + 1], wb[j + 1], c1);
      c2 = fmaf(wa[j + 2], wb[j + 2], c2);
      c3 = fmaf(wa[j + 3], wb[j + 3], c3);
    }
    W1T[tid * WS + 34] = (c0 + c1) + (c2 + c3);
  }
  __syncthreads();

  // ---- unpack x
  float x[D];
  #pragma unroll
  for (int q = 0; q < 8; ++q) {
    x[4*q+0] = xr[q].x; x[4*q+1] = xr[q].y; x[4*q+2] = xr[q].z; x[4*q+3] = xr[q].w;
  }

  float ps[D], pd[D], hreg[KPL];
  #pragma unroll
  for (int j = 0; j < D; ++j) { ps[j] = 0.0f; pd[j] = 0.0f; }

  // ================= Pass A: z, h (regs), partial s & ds/dt over this lane's k's
  #pragma unroll 2
  for (int n = 0; n < KPL; ++n) {
    const int k = L * n + kq;
    const float4* wa = reinterpret_cast<const float4*>(W1T + k * WS);
    const float4* wb = reinterpret_cast<const float4*>(W2r + k * WS);
    const float4 a8 = wa[8];                 // {W1[32,k], b1_k, c_k, pad}
    float z0 = a8.y, z1 = 0.0f, z2 = 0.0f, z3 = 0.0f;
    #pragma unroll
    for (int q = 0; q < 8; ++q) {
      float4 a = wa[q];
      z0 = fmaf(a.x, x[4*q+0], z0);
      z1 = fmaf(a.y, x[4*q+1], z1);
      z2 = fmaf(a.z, x[4*q+2], z2);
      z3 = fmaf(a.w, x[4*q+3], z3);
    }
    float z  = ((z0 + z1) + (z2 + z3)) + a8.x * tval;
    float hh = fast_tanh(z);
    hreg[n] = hh;
    float g = 1.0f - hh * hh;
    float r = g * a8.x;
    #pragma unroll
    for (int q = 0; q < 8; ++q) {
      float4 w2 = wb[q];
      ps[4*q+0] = fmaf(w2.x, hh, ps[4*q+0]);
      ps[4*q+1] = fmaf(w2.y, hh, ps[4*q+1]);
      ps[4*q+2] = fmaf(w2.z, hh, ps[4*q+2]);
      ps[4*q+3] = fmaf(w2.w, hh, ps[4*q+3]);
      pd[4*q+0] = fmaf(w2.x, r,  pd[4*q+0]);
      pd[4*q+1] = fmaf(w2.y, r,  pd[4*q+1]);
      pd[4*q+2] = fmaf(w2.z, r,  pd[4*q+2]);
      pd[4*q+3] = fmaf(w2.w, r,  pd[4*q+3]);
    }
  }

  // ---- allreduce s, dsdt across the 8 lanes of this element
  #pragma unroll
  for (int j = 0; j < D; ++j) {
    ps[j] += __shfl_xor(ps[j], 1);
    ps[j] += __shfl_xor(ps[j], 2);
    ps[j] += __shfl_xor(ps[j], 4);
    pd[j] += __shfl_xor(pd[j], 1);
    pd[j] += __shfl_xor(pd[j], 2);
    pd[j] += __shfl_xor(pd[j], 4);
  }

  // x <- v = 2s + x ; pd <- A = dsdt - hb*s   (ps dies here; shrinks live set)
  #pragma unroll
  for (int q = 0; q < 8; ++q) {
    float4 bq = reinterpret_cast<const float4*>(b2s)[q];
    float s0 = ps[4*q+0] + bq.x, s1 = ps[4*q+1] + bq.y;
    float s2 = ps[4*q+2] + bq.z, s3 = ps[4*q+3] + bq.w;
    x[4*q+0] = fmaf(2.0f, s0, x[4*q+0]);
    x[4*q+1] = fmaf(2.0f, s1, x[4*q+1]);
    x[4*q+2] = fmaf(2.0f, s2, x[4*q+2]);
    x[4*q+3] = fmaf(2.0f, s3, x[4*q+3]);
    pd[4*q+0] = fmaf(-hb, s0, pd[4*q+0]);
    pd[4*q+1] = fmaf(-hb, s1, pd[4*q+1]);
    pd[4*q+2] = fmaf(-hb, s2, pd[4*q+2]);
    pd[4*q+3] = fmaf(-hb, s3, pd[4*q+3]);
  }

  // ================= Pass B: q_k and partial grad
  float pg[D];
  #pragma unroll
  for (int j = 0; j < D; ++j) pg[j] = 0.0f;

  #pragma unroll 2
  for (int n = 0; n < KPL; ++n) {
    const int k = L * n + kq;
    const float4* wa = reinterpret_cast<const float4*>(W1T + k * WS);
    const float4* wb = reinterpret_cast<const float4*>(W2r + k * WS);

    float m0 = 0, m1 = 0, m2 = 0, m3 = 0;
    #pragma unroll
    for (int q = 0; q < 8; ++q) {
      float4 w2 = wb[q];
      m0 = fmaf(w2.x, x[4*q+0], m0);
      m1 = fmaf(w2.y, x[4*q+1], m1);
      m2 = fmaf(w2.z, x[4*q+2], m2);
      m3 = fmaf(w2.w, x[4*q+3], m3);
    }
    float m  = (m0 + m1) + (m2 + m3);
    float hh = hreg[n];
    float g  = 1.0f - hh * hh;
    float c  = wa[8].z;
    float qk = g * fmaf(-2.0f * c, hh, m);

    #pragma unroll
    for (int q = 0; q < 8; ++q) {
      float4 a = wa[q];
      pg[4*q+0] = fmaf(a.x, qk, pg[4*q+0]);
      pg[4*q+1] = fmaf(a.y, qk, pg[4*q+1]);
      pg[4*q+2] = fmaf(a.z, qk, pg[4*q+2]);
      pg[4*q+3] = fmaf(a.w, qk, pg[4*q+3]);
    }
  }

  // ---- allreduce grad partials
  #pragma unroll
  for (int j = 0; j < D; ++j) {
    pg[j] += __shfl_xor(pg[j], 1);
    pg[j] += __shfl_xor(pg[j], 2);
    pg[j] += __shfl_xor(pg[j], 4);
  }

  // ---- distributed L1: lane kq handles j = 4*kq .. 4*kq+3   (pd holds A)
  const int j0 = 4 * kq;
  float acc = fabsf(fmaf(-hb, pg[j0+0], pd[j0+0]))
            + fabsf(fmaf(-hb, pg[j0+1], pd[j0+1]))
            + fabsf(fmaf(-hb, pg[j0+2], pd[j0+2]))
            + fabsf(fmaf(-hb, pg[j0+3], pd[j0+3]));
  acc += __shfl_xor(acc, 1);
  acc += __shfl_xor(acc, 2);
  acc += __shfl_xor(acc, 4);

  if (valid && kq == 0) out[b] = acc * (1.0f / 32.0f);
}

} // namespace

extern "C" void kernel_launch(void* const* d_in, const int* in_sizes, int n_in,
                              void* d_out, int out_size, void* d_ws, size_t ws_size,
                              hipStream_t stream) {
  const float* x    = (const float*)d_in[0];
  const float* t    = (const float*)d_in[1];
  const float* beta = (const float*)d_in[2];
  const float* W1   = (const float*)d_in[3];
  const float* b1   = (const float*)d_in[4];
  const float* W2   = (const float*)d_in[5];
  const float* b2   = (const float*)d_in[6];
  float* out = (float*)d_out;

  const int Btot = in_sizes[1];  // t is [B,1]
  const int grid = (Btot + EPB - 1) / EPB;
  hipLaunchKernelGGL(fpe_kernel, dim3(grid), dim3(THREADS), 0, stream,
                     x, t, beta, W1, b1, W2, b2, out, Btot);
}